// Round 1
// baseline (967.547 us; speedup 1.0000x reference)
//
#include <hip/hip_runtime.h>
#include <cstdint>
#include <cstddef>

#define C_IN 64
#define C_TP 8
#define C_G  32
#define NB   2
#define NPTS 32768   // 32*32*32
#define MPTS 4096    // 16*16*16
#define MT   128
#define GPAD 36      // padded row for transposed g tile (multiple of 4 -> 16B aligned)

// Kernel 1: fused projection + 2x2x2 max-pool for phi (8 ch) and g (32 ch).
// One thread per (b, m). Weight reads are wave-uniform -> scalar cached.
__global__ __launch_bounds__(256) void pool_proj_kernel(
    const float* __restrict__ x,
    const float* __restrict__ w_phi,
    const float* __restrict__ w_g,
    float* __restrict__ phi_pool,   // [B][8][M]
    float* __restrict__ g_pool) {   // [B][32][M]
  int idx = blockIdx.x * 256 + threadIdx.x;
  int b = idx >> 12;              // / MPTS
  int m = idx & (MPTS - 1);
  int md = m >> 8, mh = (m >> 4) & 15, mw = m & 15;
  const float* xb = x + (size_t)b * C_IN * NPTS;

  float accp[C_TP], accg[C_G];
#pragma unroll
  for (int o = 0; o < C_TP; ++o) accp[o] = -3.0e38f;
#pragma unroll
  for (int o = 0; o < C_G; ++o) accg[o] = -3.0e38f;

#pragma unroll 1
  for (int pos = 0; pos < 8; ++pos) {
    int dd = pos >> 2, hh = (pos >> 1) & 1, ww = pos & 1;
    int n = ((md * 2 + dd) * 32 + (mh * 2 + hh)) * 32 + (mw * 2 + ww);
    float pv[C_TP], gv[C_G];
#pragma unroll
    for (int o = 0; o < C_TP; ++o) pv[o] = 0.f;
#pragma unroll
    for (int o = 0; o < C_G; ++o) gv[o] = 0.f;
#pragma unroll 4
    for (int c = 0; c < C_IN; ++c) {
      float xv = xb[(size_t)c * NPTS + n];
#pragma unroll
      for (int o = 0; o < C_TP; ++o) pv[o] = fmaf(w_phi[o * C_IN + c], xv, pv[o]);
#pragma unroll
      for (int o = 0; o < C_G; ++o) gv[o] = fmaf(w_g[o * C_IN + c], xv, gv[o]);
    }
#pragma unroll
    for (int o = 0; o < C_TP; ++o) accp[o] = fmaxf(accp[o], pv[o]);
#pragma unroll
    for (int o = 0; o < C_G; ++o) accg[o] = fmaxf(accg[o], gv[o]);
  }
#pragma unroll
  for (int o = 0; o < C_TP; ++o) phi_pool[((size_t)b * C_TP + o) * MPTS + m] = accp[o];
#pragma unroll
  for (int o = 0; o < C_G; ++o) g_pool[((size_t)b * C_G + o) * MPTS + m] = accg[o];
}

// Kernel 2: fused flash-style attention. One thread per query n.
// theta computed on the fly; phi/g tiles staged in LDS; online softmax;
// epilogue applies w_o, gamma, residual.
__global__ __launch_bounds__(256) void attn_kernel(
    const float* __restrict__ x,
    const float* __restrict__ w_theta,
    const float* __restrict__ w_o,
    const float* __restrict__ gamma_p,
    const float* __restrict__ phi_pool,
    const float* __restrict__ g_pool,
    float* __restrict__ out) {
  __shared__ float s_phi[C_TP][MT];        // 4 KB
  __shared__ float s_g[MT][GPAD];          // 18 KB, transposed: s_g[m][c]
  __shared__ float s_wo[C_IN * C_G];       // 8 KB

  int b = blockIdx.y;
  int tid = threadIdx.x;
  int n = blockIdx.x * 256 + tid;
  const float* xb = x + (size_t)b * C_IN * NPTS;
  float gamma = gamma_p[0];

  for (int i = tid; i < C_IN * C_G; i += 256) s_wo[i] = w_o[i];

  // theta[n] on the fly: th[o] = sum_c w_theta[o,c] * x[b,c,n]
  float th[C_TP];
#pragma unroll
  for (int o = 0; o < C_TP; ++o) th[o] = 0.f;
#pragma unroll 4
  for (int c = 0; c < C_IN; ++c) {
    float xv = xb[(size_t)c * NPTS + n];
#pragma unroll
    for (int o = 0; o < C_TP; ++o) th[o] = fmaf(w_theta[o * C_IN + c], xv, th[o]);
  }

  float mx = -3.0e38f, l = 0.f;
  float acc[C_G];
#pragma unroll
  for (int cg = 0; cg < C_G; ++cg) acc[cg] = 0.f;

  const float* phib = phi_pool + (size_t)b * C_TP * MPTS;
  const float* gb   = g_pool + (size_t)b * C_G * MPTS;

#pragma unroll 1
  for (int mt = 0; mt < MPTS; mt += MT) {
    __syncthreads();
#pragma unroll
    for (int i = 0; i < (C_TP * MT) / 256; ++i) {      // 4 iters
      int ii = i * 256 + tid;
      int o = ii >> 7, mm = ii & (MT - 1);
      s_phi[o][mm] = phib[(size_t)o * MPTS + mt + mm];
    }
#pragma unroll
    for (int i = 0; i < (C_G * MT) / 256; ++i) {       // 16 iters
      int ii = i * 256 + tid;
      int o = ii >> 7, mm = ii & (MT - 1);
      s_g[mm][o] = gb[(size_t)o * MPTS + mt + mm];     // transpose into LDS
    }
    __syncthreads();

#pragma unroll 2
    for (int mm = 0; mm < MT; mm += 4) {
      // 4 scores at once via float4 phi reads (broadcast across lanes)
      float4 sv = make_float4(0.f, 0.f, 0.f, 0.f);
#pragma unroll
      for (int o = 0; o < C_TP; ++o) {
        float4 pv = *(const float4*)&s_phi[o][mm];
        float t = th[o];
        sv.x = fmaf(t, pv.x, sv.x);
        sv.y = fmaf(t, pv.y, sv.y);
        sv.z = fmaf(t, pv.z, sv.z);
        sv.w = fmaf(t, pv.w, sv.w);
      }
      float s4[4] = {sv.x, sv.y, sv.z, sv.w};
#pragma unroll
      for (int j = 0; j < 4; ++j) {
        float s = s4[j];
        const float4* g4 = (const float4*)(&s_g[mm + j][0]);
        if (s <= mx) {            // common path: no new max
          float p = __expf(s - mx);
          l += p;
#pragma unroll
          for (int q = 0; q < 8; ++q) {
            float4 gv = g4[q];
            acc[4 * q + 0] = fmaf(p, gv.x, acc[4 * q + 0]);
            acc[4 * q + 1] = fmaf(p, gv.y, acc[4 * q + 1]);
            acc[4 * q + 2] = fmaf(p, gv.z, acc[4 * q + 2]);
            acc[4 * q + 3] = fmaf(p, gv.w, acc[4 * q + 3]);
          }
        } else {                  // rare: rescale running state
          float sc = __expf(mx - s);
          mx = s;
          l = fmaf(l, sc, 1.0f);
#pragma unroll
          for (int q = 0; q < 8; ++q) {
            float4 gv = g4[q];
            acc[4 * q + 0] = fmaf(acc[4 * q + 0], sc, gv.x);
            acc[4 * q + 1] = fmaf(acc[4 * q + 1], sc, gv.y);
            acc[4 * q + 2] = fmaf(acc[4 * q + 2], sc, gv.z);
            acc[4 * q + 3] = fmaf(acc[4 * q + 3], sc, gv.w);
          }
        }
      }
    }
  }

  // epilogue: out[b,co,n] = gamma * (w_o @ (acc/l))[co] + x[b,co,n]
  float inv_l = 1.0f / l;
  float gs = gamma * inv_l;
#pragma unroll 4
  for (int co = 0; co < C_IN; ++co) {
    float sum = 0.f;
    const float4* w4 = (const float4*)&s_wo[co * C_G];
#pragma unroll
    for (int q = 0; q < 8; ++q) {
      float4 wv = w4[q];
      sum = fmaf(wv.x, acc[4 * q + 0], sum);
      sum = fmaf(wv.y, acc[4 * q + 1], sum);
      sum = fmaf(wv.z, acc[4 * q + 2], sum);
      sum = fmaf(wv.w, acc[4 * q + 3], sum);
    }
    out[((size_t)b * C_IN + co) * NPTS + n] =
        fmaf(gs, sum, xb[(size_t)co * NPTS + n]);
  }
}

extern "C" void kernel_launch(void* const* d_in, const int* in_sizes, int n_in,
                              void* d_out, int out_size, void* d_ws, size_t ws_size,
                              hipStream_t stream) {
  const float* x       = (const float*)d_in[0];
  const float* w_theta = (const float*)d_in[1];
  const float* w_phi   = (const float*)d_in[2];
  const float* w_g     = (const float*)d_in[3];
  const float* w_o     = (const float*)d_in[4];
  const float* gamma   = (const float*)d_in[5];
  float* out = (float*)d_out;

  float* phi_pool = (float*)d_ws;                                  // 2*8*4096 f32 = 256 KB
  float* g_pool   = phi_pool + (size_t)NB * C_TP * MPTS;           // 2*32*4096 f32 = 1 MB

  pool_proj_kernel<<<dim3((NB * MPTS) / 256), dim3(256), 0, stream>>>(
      x, w_phi, w_g, phi_pool, g_pool);
  attn_kernel<<<dim3(NPTS / 256, NB), dim3(256), 0, stream>>>(
      x, w_theta, w_o, gamma, phi_pool, g_pool, out);
}

// Round 2
// 184.484 us; speedup vs baseline: 5.2446x; 5.2446x over previous
//
#include <hip/hip_runtime.h>
#include <cstdint>
#include <cstddef>

typedef __attribute__((ext_vector_type(4))) short short4v;
typedef __attribute__((ext_vector_type(4))) float float4v;

#define C_IN  64
#define NB    2
#define NPTS  32768   // 32*32*32
#define MPTS  4096    // 16*16*16
#define LOG2E 1.44269504088896340736f

__device__ __forceinline__ unsigned short f2bf_rne(float f) {
  unsigned int u = __builtin_bit_cast(unsigned int, f);
  u += 0x7fffu + ((u >> 16) & 1u);
  return (unsigned short)(u >> 16);
}

__device__ __forceinline__ short4v pack_bf16_trunc(float a0, float a1, float a2, float a3) {
  unsigned int u0 = __builtin_amdgcn_perm(__builtin_bit_cast(unsigned int, a1),
                                          __builtin_bit_cast(unsigned int, a0), 0x07060302u);
  unsigned int u1 = __builtin_amdgcn_perm(__builtin_bit_cast(unsigned int, a3),
                                          __builtin_bit_cast(unsigned int, a2), 0x07060302u);
  union { unsigned int u[2]; short4v s; } r;
  r.u[0] = u0; r.u[1] = u1;
  return r.s;
}

__device__ __forceinline__ short4v pack_bf16_rne(float a0, float a1, float a2, float a3) {
  short4v s;
  s[0] = (short)f2bf_rne(a0); s[1] = (short)f2bf_rne(a1);
  s[2] = (short)f2bf_rne(a2); s[3] = (short)f2bf_rne(a3);
  return s;
}

// ---------------------------------------------------------------------------
// K1: fused 1x1x1 conv + 2x2x2 maxpool for phi (8ch, scaled by log2e) and g (32ch).
// Thread layout: idx = c*8192 + (b*4096 + m), c in 0..39 (wave-uniform c).
// phi_pad: [B][M][16] bf16 (upper 8 ch zero, K-padding for MFMA A-operand)
// g_t:     [B][32][M] bf16 (channel-major for PV A-operand reads)
// ---------------------------------------------------------------------------
__global__ __launch_bounds__(256) void pool_proj(
    const float* __restrict__ x, const float* __restrict__ w_phi,
    const float* __restrict__ w_g,
    unsigned short* __restrict__ phi_pad,
    unsigned short* __restrict__ g_t) {
  int idx = blockIdx.x * 256 + threadIdx.x;
  int c  = idx >> 13;      // 0..39
  int bm = idx & 8191;     // b*4096 + m
  int b  = bm >> 12, m = bm & 4095;
  int md = m >> 8, mh = (m >> 4) & 15, mw = m & 15;
  const float* xb = x + ((size_t)b * C_IN) * NPTS
                  + ((md * 2) * 1024 + (mh * 2) * 32 + (mw * 2));
  const float* wrow = (c < 8) ? (w_phi + c * C_IN) : (w_g + (c - 8) * C_IN);

  float v0 = 0.f, v1 = 0.f, v2 = 0.f, v3 = 0.f, v4 = 0.f, v5 = 0.f, v6 = 0.f, v7 = 0.f;
#pragma unroll 8
  for (int cc = 0; cc < C_IN; ++cc) {
    float wv = wrow[cc];
    const float* xp = xb + (size_t)cc * NPTS;
    v0 = fmaf(wv, xp[0],    v0);
    v1 = fmaf(wv, xp[1],    v1);
    v2 = fmaf(wv, xp[32],   v2);
    v3 = fmaf(wv, xp[33],   v3);
    v4 = fmaf(wv, xp[1024], v4);
    v5 = fmaf(wv, xp[1025], v5);
    v6 = fmaf(wv, xp[1056], v6);
    v7 = fmaf(wv, xp[1057], v7);
  }
  float mx = fmaxf(fmaxf(fmaxf(v0, v1), fmaxf(v2, v3)),
                   fmaxf(fmaxf(v4, v5), fmaxf(v6, v7)));
  if (c < 8) {
    phi_pad[(bm << 4) + c]     = f2bf_rne(mx * LOG2E);
    phi_pad[(bm << 4) + c + 8] = 0;
  } else {
    g_t[(size_t)(b * 32 + (c - 8)) * MPTS + m] = f2bf_rne(mx);
  }
}

// ---------------------------------------------------------------------------
// K2: theta projection. Thread per (b,n). theta_pad: [B][N][16] bf16 (upper 8 zero).
// ---------------------------------------------------------------------------
__global__ __launch_bounds__(256) void theta_proj(
    const float* __restrict__ x, const float* __restrict__ w_theta,
    unsigned short* __restrict__ theta_pad) {
  int idx = blockIdx.x * 256 + threadIdx.x;   // b*NPTS + n
  int b = idx >> 15, n = idx & 32767;
  const float* xb = x + (size_t)b * C_IN * NPTS + n;
  float t[8];
#pragma unroll
  for (int o = 0; o < 8; ++o) t[o] = 0.f;
#pragma unroll 4
  for (int cc = 0; cc < C_IN; ++cc) {
    float xv = xb[(size_t)cc * NPTS];
#pragma unroll
    for (int o = 0; o < 8; ++o) t[o] = fmaf(w_theta[o * C_IN + cc], xv, t[o]);
  }
  unsigned int w0 = (unsigned int)f2bf_rne(t[0]) | ((unsigned int)f2bf_rne(t[1]) << 16);
  unsigned int w1 = (unsigned int)f2bf_rne(t[2]) | ((unsigned int)f2bf_rne(t[3]) << 16);
  unsigned int w2 = (unsigned int)f2bf_rne(t[4]) | ((unsigned int)f2bf_rne(t[5]) << 16);
  unsigned int w3 = (unsigned int)f2bf_rne(t[6]) | ((unsigned int)f2bf_rne(t[7]) << 16);
  uint4* dst = (uint4*)(theta_pad + ((size_t)idx << 4));
  dst[0] = make_uint4(w0, w1, w2, w3);
  dst[1] = make_uint4(0u, 0u, 0u, 0u);
}

// ---------------------------------------------------------------------------
// K3: MFMA flash attention (no-max softmax) + w_o epilogue + residual.
// Block = 4 waves; wave = 32 queries. Grid (NPTS/128, B).
// All MFMAs are v_mfma_f32_16x16x16_bf16; swapped operands so C/D -> B chains.
// ---------------------------------------------------------------------------
__global__ __launch_bounds__(256) void attn_mfma(
    const float* __restrict__ x, const float* __restrict__ w_o,
    const float* __restrict__ gamma_p,
    const unsigned short* __restrict__ theta_pad,
    const unsigned short* __restrict__ phi_pad,
    const unsigned short* __restrict__ g_t,
    float* __restrict__ out) {
  int tid = threadIdx.x;
  int wid = tid >> 6, lane = tid & 63;
  int l4 = lane >> 4, col = lane & 15;
  int b = blockIdx.y;
  int qb = blockIdx.x * 128 + wid * 32;

  float gamma = gamma_p[0];

  // theta B-frags (loop-invariant): lane holds theta[qb + nt*16 + col][l4*4 + e]
  const unsigned short* tb = theta_pad + ((size_t)(b * NPTS + qb) << 4) + l4 * 4;
  short4v bt0 = *(const short4v*)(tb + (col << 4));
  short4v bt1 = *(const short4v*)(tb + ((16 + col) << 4));

  // w_o A-frags with gamma folded: lane holds gamma*w_o[cot*16+col][ks*16+l4*4+e]
  short4v wo[4][2];
#pragma unroll
  for (int cot = 0; cot < 4; ++cot)
#pragma unroll
    for (int ks = 0; ks < 2; ++ks) {
      const float* wp = w_o + (cot * 16 + col) * 32 + ks * 16 + l4 * 4;
      wo[cot][ks] = pack_bf16_rne(wp[0] * gamma, wp[1] * gamma,
                                  wp[2] * gamma, wp[3] * gamma);
    }

  const unsigned short* pp  = phi_pad + (((size_t)b * MPTS) << 4) + (col << 4) + l4 * 4;
  const unsigned short* gp0 = g_t + (size_t)(b * 32 + col) * MPTS + l4 * 4;
  const unsigned short* gp1 = gp0 + (size_t)16 * MPTS;

  float4v acc00 = {0.f, 0.f, 0.f, 0.f}, acc01 = acc00, acc10 = acc00, acc11 = acc00;
  float lsum0 = 0.f, lsum1 = 0.f;

  short4v pf = *(const short4v*)pp;
  short4v g0 = *(const short4v*)gp0;
  short4v g1 = *(const short4v*)gp1;

#pragma unroll 2
  for (int kt = 0; kt < MPTS / 16; ++kt) {
    int knext = ((kt + 1) & (MPTS / 16 - 1)) * 16;
    short4v pfn = *(const short4v*)(pp + ((size_t)knext << 4));
    short4v g0n = *(const short4v*)(gp0 + knext);
    short4v g1n = *(const short4v*)(gp1 + knext);

    float4v zero4 = {0.f, 0.f, 0.f, 0.f};
    // S^T tiles: D[key][n] = sum_k phi[key][k] * theta[n][k]
    float4v s0 = __builtin_amdgcn_mfma_f32_16x16x16bf16_1k(pf, bt0, zero4, 0, 0, 0);
    float4v s1 = __builtin_amdgcn_mfma_f32_16x16x16bf16_1k(pf, bt1, zero4, 0, 0, 0);

    // P = 2^(S') (log2e folded into phi). C/D layout == B layout -> direct chain.
    float p00 = __builtin_amdgcn_exp2f(s0[0]);
    float p01 = __builtin_amdgcn_exp2f(s0[1]);
    float p02 = __builtin_amdgcn_exp2f(s0[2]);
    float p03 = __builtin_amdgcn_exp2f(s0[3]);
    float p10 = __builtin_amdgcn_exp2f(s1[0]);
    float p11 = __builtin_amdgcn_exp2f(s1[1]);
    float p12 = __builtin_amdgcn_exp2f(s1[2]);
    float p13 = __builtin_amdgcn_exp2f(s1[3]);
    lsum0 += (p00 + p01) + (p02 + p03);
    lsum1 += (p10 + p11) + (p12 + p13);
    short4v pb0 = pack_bf16_trunc(p00, p01, p02, p03);
    short4v pb1 = pack_bf16_trunc(p10, p11, p12, p13);

    // O^T[c][n] += g^T[c][key] * P^T[key][n]
    acc00 = __builtin_amdgcn_mfma_f32_16x16x16bf16_1k(g0, pb0, acc00, 0, 0, 0);
    acc01 = __builtin_amdgcn_mfma_f32_16x16x16bf16_1k(g0, pb1, acc01, 0, 0, 0);
    acc10 = __builtin_amdgcn_mfma_f32_16x16x16bf16_1k(g1, pb0, acc10, 0, 0, 0);
    acc11 = __builtin_amdgcn_mfma_f32_16x16x16bf16_1k(g1, pb1, acc11, 0, 0, 0);

    pf = pfn; g0 = g0n; g1 = g1n;
  }

  // finalize l per query column (reduce over the 4 k-groups)
  lsum0 += __shfl_xor(lsum0, 16, 64);
  lsum0 += __shfl_xor(lsum0, 32, 64);
  lsum1 += __shfl_xor(lsum1, 16, 64);
  lsum1 += __shfl_xor(lsum1, 32, 64);
  float li0 = 1.0f / lsum0;
  float li1 = 1.0f / lsum1;

  // normalized O^T as B-frags for the epilogue MFMA (C/D layout == B layout)
  short4v onb00 = pack_bf16_rne(acc00[0] * li0, acc00[1] * li0, acc00[2] * li0, acc00[3] * li0);
  short4v onb01 = pack_bf16_rne(acc01[0] * li1, acc01[1] * li1, acc01[2] * li1, acc01[3] * li1);
  short4v onb10 = pack_bf16_rne(acc10[0] * li0, acc10[1] * li0, acc10[2] * li0, acc10[3] * li0);
  short4v onb11 = pack_bf16_rne(acc11[0] * li1, acc11[1] * li1, acc11[2] * li1, acc11[3] * li1);

  // epilogue: out[co][n] = gamma*w_o[co][:] . o_norm[:][n] + x[co][n]
  float4v zero4 = {0.f, 0.f, 0.f, 0.f};
#pragma unroll
  for (int cot = 0; cot < 4; ++cot) {
#pragma unroll
    for (int nt = 0; nt < 2; ++nt) {
      short4v bfrag0 = nt ? onb01 : onb00;
      short4v bfrag1 = nt ? onb11 : onb10;
      float4v d = __builtin_amdgcn_mfma_f32_16x16x16bf16_1k(wo[cot][0], bfrag0, zero4, 0, 0, 0);
      d = __builtin_amdgcn_mfma_f32_16x16x16bf16_1k(wo[cot][1], bfrag1, d, 0, 0, 0);
      int n = qb + nt * 16 + col;
      size_t base = (size_t)(b * C_IN + cot * 16 + l4 * 4) * NPTS + n;
      const float* xp = x + base;
      float* op = out + base;
#pragma unroll
      for (int e = 0; e < 4; ++e) {
        op[(size_t)e * NPTS] = d[e] + xp[(size_t)e * NPTS];
      }
    }
  }
}

extern "C" void kernel_launch(void* const* d_in, const int* in_sizes, int n_in,
                              void* d_out, int out_size, void* d_ws, size_t ws_size,
                              hipStream_t stream) {
  const float* x       = (const float*)d_in[0];
  const float* w_theta = (const float*)d_in[1];
  const float* w_phi   = (const float*)d_in[2];
  const float* w_g     = (const float*)d_in[3];
  const float* w_o     = (const float*)d_in[4];
  const float* gamma   = (const float*)d_in[5];
  float* out = (float*)d_out;

  // ws carve (bf16 buffers):
  unsigned short* theta_pad = (unsigned short*)d_ws;                    // B*N*16 = 1 MB
  unsigned short* phi_pad   = theta_pad + (size_t)NB * NPTS * 16;       // B*M*16 = 256 KB
  unsigned short* g_t       = phi_pad + (size_t)NB * MPTS * 16;         // B*32*M = 512 KB

  pool_proj<<<dim3((40 * NB * MPTS) / 256), dim3(256), 0, stream>>>(
      x, w_phi, w_g, phi_pad, g_t);
  theta_proj<<<dim3((NB * NPTS) / 256), dim3(256), 0, stream>>>(
      x, w_theta, theta_pad);
  attn_mfma<<<dim3(NPTS / 128, NB), dim3(256), 0, stream>>>(
      x, w_o, gamma, theta_pad, phi_pad, g_t, out);
}

// Round 3
// 105.740 us; speedup vs baseline: 9.1503x; 1.7447x over previous
//
#include <hip/hip_runtime.h>
#include <cstdint>
#include <cstddef>

typedef __attribute__((ext_vector_type(4))) short short4v;
typedef __attribute__((ext_vector_type(4))) float float4v;

#define C_IN  64
#define NB    2
#define NPTS  32768   // 32*32*32
#define MPTS  4096    // 16*16*16
#define LOG2E 1.44269504088896340736f
#define KT    64              // keys per staged tile
#define NTILE (MPTS / KT)     // 64

__device__ __forceinline__ unsigned short f2bf_rne(float f) {
  unsigned int u = __builtin_bit_cast(unsigned int, f);
  u += 0x7fffu + ((u >> 16) & 1u);
  return (unsigned short)(u >> 16);
}

__device__ __forceinline__ short4v pack_bf16_trunc(float a0, float a1, float a2, float a3) {
  unsigned int u0 = __builtin_amdgcn_perm(__builtin_bit_cast(unsigned int, a1),
                                          __builtin_bit_cast(unsigned int, a0), 0x07060302u);
  unsigned int u1 = __builtin_amdgcn_perm(__builtin_bit_cast(unsigned int, a3),
                                          __builtin_bit_cast(unsigned int, a2), 0x07060302u);
  union { unsigned int u[2]; short4v s; } r;
  r.u[0] = u0; r.u[1] = u1;
  return r.s;
}

__device__ __forceinline__ short4v pack_bf16_rne(float a0, float a1, float a2, float a3) {
  short4v s;
  s[0] = (short)f2bf_rne(a0); s[1] = (short)f2bf_rne(a1);
  s[2] = (short)f2bf_rne(a2); s[3] = (short)f2bf_rne(a3);
  return s;
}

__device__ __forceinline__ void gl_lds16(const unsigned short* g, unsigned short* l) {
  __builtin_amdgcn_global_load_lds(
      (const __attribute__((address_space(1))) void*)g,
      (__attribute__((address_space(3))) void*)l, 16, 0, 0);
}

// ---------------------------------------------------------------------------
// K1: fused 1x1x1 conv + 2x2x2 maxpool. Thread = (cgroup of 4 out-ch, b, m).
// cg 0..1 -> phi ch 0..7 (scaled by log2e); cg 2..9 -> g ch 0..31.
// phi_pad: [B][M][16] bf16 (upper 8 zero)
// g_f:     [B][M/16][2][16][16] bf16  (kt16, half, ch16, key16) fragment-tiled
// ---------------------------------------------------------------------------
__global__ __launch_bounds__(256) void pool_proj(
    const float* __restrict__ x, const float* __restrict__ w_phi,
    const float* __restrict__ w_g,
    unsigned short* __restrict__ phi_pad,
    unsigned short* __restrict__ g_f) {
  int idx = blockIdx.x * 256 + threadIdx.x;
  int cg = idx >> 13;          // 0..9
  int bm = idx & 8191;
  int b = bm >> 12, m = bm & 4095;
  int md = m >> 8, mh = (m >> 4) & 15, mw = m & 15;
  const float* xb = x + (size_t)b * C_IN * NPTS
                  + ((md * 2) * 1024 + (mh * 2) * 32 + (mw * 2));
  const float* wbase = (cg < 2) ? (w_phi + cg * 4 * C_IN)
                                : (w_g + (cg * 4 - 8) * C_IN);

  float acc[4][8];
#pragma unroll
  for (int o = 0; o < 4; ++o)
#pragma unroll
    for (int p = 0; p < 8; ++p) acc[o][p] = 0.f;

#pragma unroll 4
  for (int cc = 0; cc < C_IN; ++cc) {
    const float* xp = xb + (size_t)cc * NPTS;
    float2 p01 = *(const float2*)(xp + 0);
    float2 p23 = *(const float2*)(xp + 32);
    float2 p45 = *(const float2*)(xp + 1024);
    float2 p67 = *(const float2*)(xp + 1056);
#pragma unroll
    for (int o = 0; o < 4; ++o) {
      float wv = wbase[o * C_IN + cc];
      acc[o][0] = fmaf(wv, p01.x, acc[o][0]);
      acc[o][1] = fmaf(wv, p01.y, acc[o][1]);
      acc[o][2] = fmaf(wv, p23.x, acc[o][2]);
      acc[o][3] = fmaf(wv, p23.y, acc[o][3]);
      acc[o][4] = fmaf(wv, p45.x, acc[o][4]);
      acc[o][5] = fmaf(wv, p45.y, acc[o][5]);
      acc[o][6] = fmaf(wv, p67.x, acc[o][6]);
      acc[o][7] = fmaf(wv, p67.y, acc[o][7]);
    }
  }
  float mx[4];
#pragma unroll
  for (int o = 0; o < 4; ++o) {
    mx[o] = fmaxf(fmaxf(fmaxf(acc[o][0], acc[o][1]), fmaxf(acc[o][2], acc[o][3])),
                  fmaxf(fmaxf(acc[o][4], acc[o][5]), fmaxf(acc[o][6], acc[o][7])));
  }
  if (cg < 2) {
    int c0 = cg * 4;
#pragma unroll
    for (int o = 0; o < 4; ++o) {
      phi_pad[(bm << 4) + c0 + o] = f2bf_rne(mx[o] * LOG2E);
      phi_pad[(bm << 4) + 8 + c0 + o] = 0;
    }
  } else {
    int gc0 = cg * 4 - 8;
    int kt16 = m >> 4, kr = m & 15;
#pragma unroll
    for (int o = 0; o < 4; ++o) {
      int c = gc0 + o;
      g_f[((((size_t)b * 256 + kt16) * 2 + (c >> 4)) * 16 + (c & 15)) * 16 + kr] =
          f2bf_rne(mx[o]);
    }
  }
}

// ---------------------------------------------------------------------------
// K2: theta projection. Thread per (b,n). theta_pad: [B][N][16] bf16 (upper 8 zero).
// ---------------------------------------------------------------------------
__global__ __launch_bounds__(256) void theta_proj(
    const float* __restrict__ x, const float* __restrict__ w_theta,
    unsigned short* __restrict__ theta_pad) {
  int idx = blockIdx.x * 256 + threadIdx.x;   // b*NPTS + n
  int b = idx >> 15, n = idx & 32767;
  const float* xb = x + (size_t)b * C_IN * NPTS + n;
  float t[8];
#pragma unroll
  for (int o = 0; o < 8; ++o) t[o] = 0.f;
#pragma unroll 4
  for (int cc = 0; cc < C_IN; ++cc) {
    float xv = xb[(size_t)cc * NPTS];
#pragma unroll
    for (int o = 0; o < 8; ++o) t[o] = fmaf(w_theta[o * C_IN + cc], xv, t[o]);
  }
  unsigned int w0 = (unsigned int)f2bf_rne(t[0]) | ((unsigned int)f2bf_rne(t[1]) << 16);
  unsigned int w1 = (unsigned int)f2bf_rne(t[2]) | ((unsigned int)f2bf_rne(t[3]) << 16);
  unsigned int w2 = (unsigned int)f2bf_rne(t[4]) | ((unsigned int)f2bf_rne(t[5]) << 16);
  unsigned int w3 = (unsigned int)f2bf_rne(t[6]) | ((unsigned int)f2bf_rne(t[7]) << 16);
  uint4* dst = (uint4*)(theta_pad + ((size_t)idx << 4));
  dst[0] = make_uint4(w0, w1, w2, w3);
  dst[1] = make_uint4(0u, 0u, 0u, 0u);
}

// ---------------------------------------------------------------------------
// K3: MFMA flash attention (no-max softmax) + w_o epilogue + residual.
// Block = 4 waves (128 queries); keys staged in LDS (double-buffered KT=64)
// via global_load_lds, shared by all 4 waves.
// ---------------------------------------------------------------------------
__global__ __launch_bounds__(256) void attn_mfma(
    const float* __restrict__ x, const float* __restrict__ w_o,
    const float* __restrict__ gamma_p,
    const unsigned short* __restrict__ theta_pad,
    const unsigned short* __restrict__ phi_pad,
    const unsigned short* __restrict__ g_f,
    float* __restrict__ out) {
  __shared__ unsigned short s_phi[2][KT * 16];          // 2 KB per buf
  __shared__ unsigned short s_g[2][(KT / 16) * 512];    // 4 KB per buf

  int tid = threadIdx.x;
  int wid = tid >> 6, lane = tid & 63;
  int l4 = lane >> 4, col = lane & 15;
  int b = blockIdx.y;
  int qb = blockIdx.x * 128 + wid * 32;

  float gamma = gamma_p[0];

  // theta B-frags (loop-invariant)
  const unsigned short* tb = theta_pad + ((size_t)(b * NPTS + qb) << 4) + l4 * 4;
  short4v bt0 = *(const short4v*)(tb + (col << 4));
  short4v bt1 = *(const short4v*)(tb + ((16 + col) << 4));

  // w_o A-frags with gamma folded
  short4v wo[4][2];
#pragma unroll
  for (int cot = 0; cot < 4; ++cot)
#pragma unroll
    for (int ks = 0; ks < 2; ++ks) {
      const float* wp = w_o + (cot * 16 + col) * 32 + ks * 16 + l4 * 4;
      wo[cot][ks] = pack_bf16_rne(wp[0] * gamma, wp[1] * gamma,
                                  wp[2] * gamma, wp[3] * gamma);
    }

  const unsigned short* phib = phi_pad + ((size_t)b * MPTS << 4);
  const unsigned short* gb   = g_f + (size_t)b * (MPTS / 16) * 512;

  float4v acc00 = {0.f, 0.f, 0.f, 0.f}, acc01 = acc00, acc10 = acc00, acc11 = acc00;
  float lsum0 = 0.f, lsum1 = 0.f;

  // prologue: stage tile 0 into buf 0
  {
    gl_lds16(gb + 0 * 2048 + wid * 512 + lane * 8, &s_g[0][wid * 512]);
    if (wid < 2)
      gl_lds16(phib + 0 * 1024 + wid * 512 + lane * 8, &s_phi[0][wid * 512]);
  }
  __syncthreads();

#pragma unroll 1
  for (int t = 0; t < NTILE; ++t) {
    int cur = t & 1;
    if (t + 1 < NTILE) {
      gl_lds16(gb + (size_t)(t + 1) * 2048 + wid * 512 + lane * 8,
               &s_g[cur ^ 1][wid * 512]);
      if (wid < 2)
        gl_lds16(phib + (size_t)(t + 1) * 1024 + wid * 512 + lane * 8,
                 &s_phi[cur ^ 1][wid * 512]);
    }

#pragma unroll
    for (int st = 0; st < 4; ++st) {
      int fb = st * 256 + col * 16 + l4 * 4;
      short4v pf = *(const short4v*)&s_phi[cur][fb];
      int gv = st * 512 + col * 16 + l4 * 4;
      short4v g0 = *(const short4v*)&s_g[cur][gv];
      short4v g1 = *(const short4v*)&s_g[cur][gv + 256];

      float4v zero4 = {0.f, 0.f, 0.f, 0.f};
      float4v s0 = __builtin_amdgcn_mfma_f32_16x16x16bf16_1k(pf, bt0, zero4, 0, 0, 0);
      float4v s1 = __builtin_amdgcn_mfma_f32_16x16x16bf16_1k(pf, bt1, zero4, 0, 0, 0);

      float p00 = __builtin_amdgcn_exp2f(s0[0]);
      float p01 = __builtin_amdgcn_exp2f(s0[1]);
      float p02 = __builtin_amdgcn_exp2f(s0[2]);
      float p03 = __builtin_amdgcn_exp2f(s0[3]);
      float p10 = __builtin_amdgcn_exp2f(s1[0]);
      float p11 = __builtin_amdgcn_exp2f(s1[1]);
      float p12 = __builtin_amdgcn_exp2f(s1[2]);
      float p13 = __builtin_amdgcn_exp2f(s1[3]);
      lsum0 += (p00 + p01) + (p02 + p03);
      lsum1 += (p10 + p11) + (p12 + p13);
      short4v pb0 = pack_bf16_trunc(p00, p01, p02, p03);
      short4v pb1 = pack_bf16_trunc(p10, p11, p12, p13);

      acc00 = __builtin_amdgcn_mfma_f32_16x16x16bf16_1k(g0, pb0, acc00, 0, 0, 0);
      acc01 = __builtin_amdgcn_mfma_f32_16x16x16bf16_1k(g0, pb1, acc01, 0, 0, 0);
      acc10 = __builtin_amdgcn_mfma_f32_16x16x16bf16_1k(g1, pb0, acc10, 0, 0, 0);
      acc11 = __builtin_amdgcn_mfma_f32_16x16x16bf16_1k(g1, pb1, acc11, 0, 0, 0);
    }
    __syncthreads();   // drains vmcnt (next tile staged) + protects cur buf reuse
  }

  // finalize l per query column
  lsum0 += __shfl_xor(lsum0, 16, 64);
  lsum0 += __shfl_xor(lsum0, 32, 64);
  lsum1 += __shfl_xor(lsum1, 16, 64);
  lsum1 += __shfl_xor(lsum1, 32, 64);
  float li0 = 1.0f / lsum0;
  float li1 = 1.0f / lsum1;

  short4v onb00 = pack_bf16_rne(acc00[0] * li0, acc00[1] * li0, acc00[2] * li0, acc00[3] * li0);
  short4v onb01 = pack_bf16_rne(acc01[0] * li1, acc01[1] * li1, acc01[2] * li1, acc01[3] * li1);
  short4v onb10 = pack_bf16_rne(acc10[0] * li0, acc10[1] * li0, acc10[2] * li0, acc10[3] * li0);
  short4v onb11 = pack_bf16_rne(acc11[0] * li1, acc11[1] * li1, acc11[2] * li1, acc11[3] * li1);

  float4v zero4 = {0.f, 0.f, 0.f, 0.f};
#pragma unroll
  for (int cot = 0; cot < 4; ++cot) {
#pragma unroll
    for (int nt = 0; nt < 2; ++nt) {
      short4v bfrag0 = nt ? onb01 : onb00;
      short4v bfrag1 = nt ? onb11 : onb10;
      float4v d = __builtin_amdgcn_mfma_f32_16x16x16bf16_1k(wo[cot][0], bfrag0, zero4, 0, 0, 0);
      d = __builtin_amdgcn_mfma_f32_16x16x16bf16_1k(wo[cot][1], bfrag1, d, 0, 0, 0);
      int n = qb + nt * 16 + col;
      size_t base = (size_t)(b * C_IN + cot * 16 + l4 * 4) * NPTS + n;
      const float* xp = x + base;
      float* op = out + base;
#pragma unroll
      for (int e = 0; e < 4; ++e) {
        op[(size_t)e * NPTS] = d[e] + xp[(size_t)e * NPTS];
      }
    }
  }
}

extern "C" void kernel_launch(void* const* d_in, const int* in_sizes, int n_in,
                              void* d_out, int out_size, void* d_ws, size_t ws_size,
                              hipStream_t stream) {
  const float* x       = (const float*)d_in[0];
  const float* w_theta = (const float*)d_in[1];
  const float* w_phi   = (const float*)d_in[2];
  const float* w_g     = (const float*)d_in[3];
  const float* w_o     = (const float*)d_in[4];
  const float* gamma   = (const float*)d_in[5];
  float* out = (float*)d_out;

  unsigned short* theta_pad = (unsigned short*)d_ws;                    // 2 MB
  unsigned short* phi_pad   = theta_pad + (size_t)NB * NPTS * 16;       // 256 KB
  unsigned short* g_f       = phi_pad + (size_t)NB * MPTS * 16;         // 512 KB

  pool_proj<<<dim3((10 * NB * MPTS) / 256), dim3(256), 0, stream>>>(
      x, w_phi, w_g, phi_pad, g_f);
  theta_proj<<<dim3((NB * NPTS) / 256), dim3(256), 0, stream>>>(
      x, w_theta, theta_pad);
  attn_mfma<<<dim3(NPTS / 128, NB), dim3(256), 0, stream>>>(
      x, w_o, gamma, theta_pad, phi_pad, g_f, out);
}

// Round 4
// 91.482 us; speedup vs baseline: 10.5764x; 1.1559x over previous
//
#include <hip/hip_runtime.h>
#include <cstdint>
#include <cstddef>

typedef __attribute__((ext_vector_type(4))) short short4v;
typedef __attribute__((ext_vector_type(4))) float float4v;

#define C_IN  64
#define NB    2
#define NPTS  32768   // 32*32*32
#define MPTS  4096    // 16*16*16
#define LOG2E 1.44269504088896340736f
#define KT    64              // keys per staged tile
#define NTILE (MPTS / KT)     // 64
#define KSPLIT 2
#define QTILES (NPTS / 32)    // 1024 q-tiles of 32 per batch

__device__ __forceinline__ unsigned short f2bf_rne(float f) {
  unsigned int u = __builtin_bit_cast(unsigned int, f);
  u += 0x7fffu + ((u >> 16) & 1u);
  return (unsigned short)(u >> 16);
}

__device__ __forceinline__ short4v pack_bf16_trunc(float a0, float a1, float a2, float a3) {
  unsigned int u0 = __builtin_amdgcn_perm(__builtin_bit_cast(unsigned int, a1),
                                          __builtin_bit_cast(unsigned int, a0), 0x07060302u);
  unsigned int u1 = __builtin_amdgcn_perm(__builtin_bit_cast(unsigned int, a3),
                                          __builtin_bit_cast(unsigned int, a2), 0x07060302u);
  union { unsigned int u[2]; short4v s; } r;
  r.u[0] = u0; r.u[1] = u1;
  return r.s;
}

__device__ __forceinline__ short4v pack_bf16_rne(float a0, float a1, float a2, float a3) {
  short4v s;
  s[0] = (short)f2bf_rne(a0); s[1] = (short)f2bf_rne(a1);
  s[2] = (short)f2bf_rne(a2); s[3] = (short)f2bf_rne(a3);
  return s;
}

__device__ __forceinline__ void gl_lds16(const unsigned short* g, unsigned short* l) {
  __builtin_amdgcn_global_load_lds(
      (const __attribute__((address_space(1))) void*)g,
      (__attribute__((address_space(3))) void*)l, 16, 0, 0);
}

// ---------------------------------------------------------------------------
// Prep (fused): blocks [0,320) = pool+proj for phi/g; blocks [320,576) = theta.
// phi_pad: [B][M][16] bf16 (upper 8 zero, log2e folded)
// g_f:     [B][M/16][2][16][16] bf16 (kt16, half, ch16, key16) fragment-tiled
// theta_pad: [B][N][16] bf16 (upper 8 zero)
// ---------------------------------------------------------------------------
__device__ void pool_body(int idx, const float* __restrict__ x,
                          const float* __restrict__ w_phi,
                          const float* __restrict__ w_g,
                          unsigned short* __restrict__ phi_pad,
                          unsigned short* __restrict__ g_f) {
  int cg = idx >> 13;          // 0..9
  int bm = idx & 8191;
  int b = bm >> 12, m = bm & 4095;
  int md = m >> 8, mh = (m >> 4) & 15, mw = m & 15;
  const float* xb = x + (size_t)b * C_IN * NPTS
                  + ((md * 2) * 1024 + (mh * 2) * 32 + (mw * 2));
  const float* wbase = (cg < 2) ? (w_phi + cg * 4 * C_IN)
                                : (w_g + (cg * 4 - 8) * C_IN);

  float acc[4][8];
#pragma unroll
  for (int o = 0; o < 4; ++o)
#pragma unroll
    for (int p = 0; p < 8; ++p) acc[o][p] = 0.f;

#pragma unroll 4
  for (int cc = 0; cc < C_IN; ++cc) {
    const float* xp = xb + (size_t)cc * NPTS;
    float2 p01 = *(const float2*)(xp + 0);
    float2 p23 = *(const float2*)(xp + 32);
    float2 p45 = *(const float2*)(xp + 1024);
    float2 p67 = *(const float2*)(xp + 1056);
#pragma unroll
    for (int o = 0; o < 4; ++o) {
      float wv = wbase[o * C_IN + cc];
      acc[o][0] = fmaf(wv, p01.x, acc[o][0]);
      acc[o][1] = fmaf(wv, p01.y, acc[o][1]);
      acc[o][2] = fmaf(wv, p23.x, acc[o][2]);
      acc[o][3] = fmaf(wv, p23.y, acc[o][3]);
      acc[o][4] = fmaf(wv, p45.x, acc[o][4]);
      acc[o][5] = fmaf(wv, p45.y, acc[o][5]);
      acc[o][6] = fmaf(wv, p67.x, acc[o][6]);
      acc[o][7] = fmaf(wv, p67.y, acc[o][7]);
    }
  }
  float mx[4];
#pragma unroll
  for (int o = 0; o < 4; ++o) {
    mx[o] = fmaxf(fmaxf(fmaxf(acc[o][0], acc[o][1]), fmaxf(acc[o][2], acc[o][3])),
                  fmaxf(fmaxf(acc[o][4], acc[o][5]), fmaxf(acc[o][6], acc[o][7])));
  }
  if (cg < 2) {
    int c0 = cg * 4;
#pragma unroll
    for (int o = 0; o < 4; ++o) {
      phi_pad[(bm << 4) + c0 + o] = f2bf_rne(mx[o] * LOG2E);
      phi_pad[(bm << 4) + 8 + c0 + o] = 0;
    }
  } else {
    int gc0 = cg * 4 - 8;
    int kt16 = m >> 4, kr = m & 15;
#pragma unroll
    for (int o = 0; o < 4; ++o) {
      int c = gc0 + o;
      g_f[((((size_t)b * 256 + kt16) * 2 + (c >> 4)) * 16 + (c & 15)) * 16 + kr] =
          f2bf_rne(mx[o]);
    }
  }
}

__device__ void theta_body(int idx, const float* __restrict__ x,
                           const float* __restrict__ w_theta,
                           unsigned short* __restrict__ theta_pad) {
  int b = idx >> 15, n = idx & 32767;
  const float* xb = x + (size_t)b * C_IN * NPTS + n;
  float t[8];
#pragma unroll
  for (int o = 0; o < 8; ++o) t[o] = 0.f;
#pragma unroll 4
  for (int cc = 0; cc < C_IN; ++cc) {
    float xv = xb[(size_t)cc * NPTS];
#pragma unroll
    for (int o = 0; o < 8; ++o) t[o] = fmaf(w_theta[o * C_IN + cc], xv, t[o]);
  }
  unsigned int w0 = (unsigned int)f2bf_rne(t[0]) | ((unsigned int)f2bf_rne(t[1]) << 16);
  unsigned int w1 = (unsigned int)f2bf_rne(t[2]) | ((unsigned int)f2bf_rne(t[3]) << 16);
  unsigned int w2 = (unsigned int)f2bf_rne(t[4]) | ((unsigned int)f2bf_rne(t[5]) << 16);
  unsigned int w3 = (unsigned int)f2bf_rne(t[6]) | ((unsigned int)f2bf_rne(t[7]) << 16);
  uint4* dst = (uint4*)(theta_pad + ((size_t)idx << 4));
  dst[0] = make_uint4(w0, w1, w2, w3);
  dst[1] = make_uint4(0u, 0u, 0u, 0u);
}

__global__ __launch_bounds__(256) void prep_fused(
    const float* __restrict__ x, const float* __restrict__ w_theta,
    const float* __restrict__ w_phi, const float* __restrict__ w_g,
    unsigned short* __restrict__ theta_pad,
    unsigned short* __restrict__ phi_pad,
    unsigned short* __restrict__ g_f) {
  int gb = blockIdx.x;
  if (gb < 320) {
    pool_body(gb * 256 + threadIdx.x, x, w_phi, w_g, phi_pad, g_f);
  } else {
    theta_body((gb - 320) * 256 + threadIdx.x, x, w_theta, theta_pad);
  }
}

// ---------------------------------------------------------------------------
// Pass 1: split-K flash attention partials. Grid (NPTS/128, NB*KSPLIT).
// Each block: 128 queries x 2048 keys -> unnormalized O^T partial + lsum.
// opart: [B][KSPLIT][QTILES][4 accs][64 lanes] float4 (lane-major, coalesced)
// lbuf:  [B][KSPLIT][QTILES][32] f32
// ---------------------------------------------------------------------------
__global__ __launch_bounds__(256) void attn_split(
    const unsigned short* __restrict__ theta_pad,
    const unsigned short* __restrict__ phi_pad,
    const unsigned short* __restrict__ g_f,
    float4v* __restrict__ opart,
    float* __restrict__ lbuf) {
  __shared__ unsigned short s_phi[2][KT * 16];
  __shared__ unsigned short s_g[2][(KT / 16) * 512];

  int tid = threadIdx.x;
  int wid = tid >> 6, lane = tid & 63;
  int l4 = lane >> 4, col = lane & 15;
  int b = blockIdx.y >> 1;
  int ks = blockIdx.y & 1;
  int qb = blockIdx.x * 128 + wid * 32;
  int t0 = ks * (NTILE / KSPLIT);            // 32 tiles per split
  int t1 = t0 + NTILE / KSPLIT;

  const unsigned short* tb = theta_pad + ((size_t)(b * NPTS + qb) << 4) + l4 * 4;
  short4v bt0 = *(const short4v*)(tb + (col << 4));
  short4v bt1 = *(const short4v*)(tb + ((16 + col) << 4));

  const unsigned short* phib = phi_pad + ((size_t)b * MPTS << 4);
  const unsigned short* gb   = g_f + (size_t)b * (MPTS / 16) * 512;

  float4v acc00 = {0.f, 0.f, 0.f, 0.f}, acc01 = acc00, acc10 = acc00, acc11 = acc00;
  float lsum0 = 0.f, lsum1 = 0.f;

  gl_lds16(gb + (size_t)t0 * 2048 + wid * 512 + lane * 8, &s_g[0][wid * 512]);
  if (wid < 2)
    gl_lds16(phib + (size_t)t0 * 1024 + wid * 512 + lane * 8, &s_phi[0][wid * 512]);
  __syncthreads();

#pragma unroll 1
  for (int t = t0; t < t1; ++t) {
    int cur = t & 1;
    if (t + 1 < t1) {
      gl_lds16(gb + (size_t)(t + 1) * 2048 + wid * 512 + lane * 8,
               &s_g[cur ^ 1][wid * 512]);
      if (wid < 2)
        gl_lds16(phib + (size_t)(t + 1) * 1024 + wid * 512 + lane * 8,
                 &s_phi[cur ^ 1][wid * 512]);
    }

#pragma unroll
    for (int st = 0; st < 4; ++st) {
      int fb = st * 256 + col * 16 + l4 * 4;
      short4v pf = *(const short4v*)&s_phi[cur][fb];
      int gv = st * 512 + col * 16 + l4 * 4;
      short4v g0 = *(const short4v*)&s_g[cur][gv];
      short4v g1 = *(const short4v*)&s_g[cur][gv + 256];

      float4v zero4 = {0.f, 0.f, 0.f, 0.f};
      float4v s0 = __builtin_amdgcn_mfma_f32_16x16x16bf16_1k(pf, bt0, zero4, 0, 0, 0);
      float4v s1 = __builtin_amdgcn_mfma_f32_16x16x16bf16_1k(pf, bt1, zero4, 0, 0, 0);

      float p00 = __builtin_amdgcn_exp2f(s0[0]);
      float p01 = __builtin_amdgcn_exp2f(s0[1]);
      float p02 = __builtin_amdgcn_exp2f(s0[2]);
      float p03 = __builtin_amdgcn_exp2f(s0[3]);
      float p10 = __builtin_amdgcn_exp2f(s1[0]);
      float p11 = __builtin_amdgcn_exp2f(s1[1]);
      float p12 = __builtin_amdgcn_exp2f(s1[2]);
      float p13 = __builtin_amdgcn_exp2f(s1[3]);
      lsum0 += (p00 + p01) + (p02 + p03);
      lsum1 += (p10 + p11) + (p12 + p13);
      short4v pb0 = pack_bf16_trunc(p00, p01, p02, p03);
      short4v pb1 = pack_bf16_trunc(p10, p11, p12, p13);

      acc00 = __builtin_amdgcn_mfma_f32_16x16x16bf16_1k(g0, pb0, acc00, 0, 0, 0);
      acc01 = __builtin_amdgcn_mfma_f32_16x16x16bf16_1k(g0, pb1, acc01, 0, 0, 0);
      acc10 = __builtin_amdgcn_mfma_f32_16x16x16bf16_1k(g1, pb0, acc10, 0, 0, 0);
      acc11 = __builtin_amdgcn_mfma_f32_16x16x16bf16_1k(g1, pb1, acc11, 0, 0, 0);
    }
    __syncthreads();
  }

  lsum0 += __shfl_xor(lsum0, 16, 64);
  lsum0 += __shfl_xor(lsum0, 32, 64);
  lsum1 += __shfl_xor(lsum1, 16, 64);
  lsum1 += __shfl_xor(lsum1, 32, 64);

  int qt = blockIdx.x * 4 + wid;
  size_t obase = (((size_t)(b * KSPLIT + ks) * QTILES + qt) * 4) * 64 + lane;
  opart[obase + 0 * 64] = acc00;
  opart[obase + 1 * 64] = acc01;
  opart[obase + 2 * 64] = acc10;
  opart[obase + 3 * 64] = acc11;
  if (lane < 32) {
    lbuf[((size_t)(b * KSPLIT + ks) * QTILES + qt) * 32 + lane] =
        (lane < 16) ? lsum0 : lsum1;
  }
}

// ---------------------------------------------------------------------------
// Pass 2: combine partials, normalize, w_o epilogue MFMA, gamma, residual.
// Grid (NPTS/128, NB), block 256.
// ---------------------------------------------------------------------------
__global__ __launch_bounds__(256) void attn_combine(
    const float* __restrict__ x, const float* __restrict__ w_o,
    const float* __restrict__ gamma_p,
    const float4v* __restrict__ opart,
    const float* __restrict__ lbuf,
    float* __restrict__ out) {
  int tid = threadIdx.x;
  int wid = tid >> 6, lane = tid & 63;
  int l4 = lane >> 4, col = lane & 15;
  int b = blockIdx.y;
  int qt = blockIdx.x * 4 + wid;
  int qb = qt * 32;

  float gamma = gamma_p[0];

  short4v wo[4][2];
#pragma unroll
  for (int cot = 0; cot < 4; ++cot)
#pragma unroll
    for (int ksw = 0; ksw < 2; ++ksw) {
      const float* wp = w_o + (cot * 16 + col) * 32 + ksw * 16 + l4 * 4;
      wo[cot][ksw] = pack_bf16_rne(wp[0] * gamma, wp[1] * gamma,
                                   wp[2] * gamma, wp[3] * gamma);
    }

  // combine partials
  size_t ob0 = (((size_t)(b * KSPLIT + 0) * QTILES + qt) * 4) * 64 + lane;
  size_t ob1 = (((size_t)(b * KSPLIT + 1) * QTILES + qt) * 4) * 64 + lane;
  float4v a0 = opart[ob0 + 0 * 64] + opart[ob1 + 0 * 64];
  float4v a1 = opart[ob0 + 1 * 64] + opart[ob1 + 1 * 64];
  float4v a2 = opart[ob0 + 2 * 64] + opart[ob1 + 2 * 64];
  float4v a3 = opart[ob0 + 3 * 64] + opart[ob1 + 3 * 64];

  const float* lb0 = lbuf + ((size_t)(b * KSPLIT + 0) * QTILES + qt) * 32;
  const float* lb1 = lbuf + ((size_t)(b * KSPLIT + 1) * QTILES + qt) * 32;
  float li0 = 1.0f / (lb0[col] + lb1[col]);
  float li1 = 1.0f / (lb0[col + 16] + lb1[col + 16]);

  short4v onb00 = pack_bf16_rne(a0[0] * li0, a0[1] * li0, a0[2] * li0, a0[3] * li0);
  short4v onb01 = pack_bf16_rne(a1[0] * li1, a1[1] * li1, a1[2] * li1, a1[3] * li1);
  short4v onb10 = pack_bf16_rne(a2[0] * li0, a2[1] * li0, a2[2] * li0, a2[3] * li0);
  short4v onb11 = pack_bf16_rne(a3[0] * li1, a3[1] * li1, a3[2] * li1, a3[3] * li1);

  float4v zero4 = {0.f, 0.f, 0.f, 0.f};
#pragma unroll
  for (int cot = 0; cot < 4; ++cot) {
#pragma unroll
    for (int nt = 0; nt < 2; ++nt) {
      short4v bfrag0 = nt ? onb01 : onb00;
      short4v bfrag1 = nt ? onb11 : onb10;
      float4v d = __builtin_amdgcn_mfma_f32_16x16x16bf16_1k(wo[cot][0], bfrag0, zero4, 0, 0, 0);
      d = __builtin_amdgcn_mfma_f32_16x16x16bf16_1k(wo[cot][1], bfrag1, d, 0, 0, 0);
      int n = qb + nt * 16 + col;
      size_t base = (size_t)(b * C_IN + cot * 16 + l4 * 4) * NPTS + n;
      const float* xp = x + base;
      float* op = out + base;
#pragma unroll
      for (int e = 0; e < 4; ++e) {
        op[(size_t)e * NPTS] = d[e] + xp[(size_t)e * NPTS];
      }
    }
  }
}

// ---------------------------------------------------------------------------
// Fallback single-pass attention (round-3 proven) for small ws_size.
// ---------------------------------------------------------------------------
__global__ __launch_bounds__(256) void attn_mfma(
    const float* __restrict__ x, const float* __restrict__ w_o,
    const float* __restrict__ gamma_p,
    const unsigned short* __restrict__ theta_pad,
    const unsigned short* __restrict__ phi_pad,
    const unsigned short* __restrict__ g_f,
    float* __restrict__ out) {
  __shared__ unsigned short s_phi[2][KT * 16];
  __shared__ unsigned short s_g[2][(KT / 16) * 512];

  int tid = threadIdx.x;
  int wid = tid >> 6, lane = tid & 63;
  int l4 = lane >> 4, col = lane & 15;
  int b = blockIdx.y;
  int qb = blockIdx.x * 128 + wid * 32;

  float gamma = gamma_p[0];

  const unsigned short* tb = theta_pad + ((size_t)(b * NPTS + qb) << 4) + l4 * 4;
  short4v bt0 = *(const short4v*)(tb + (col << 4));
  short4v bt1 = *(const short4v*)(tb + ((16 + col) << 4));

  short4v wo[4][2];
#pragma unroll
  for (int cot = 0; cot < 4; ++cot)
#pragma unroll
    for (int ksw = 0; ksw < 2; ++ksw) {
      const float* wp = w_o + (cot * 16 + col) * 32 + ksw * 16 + l4 * 4;
      wo[cot][ksw] = pack_bf16_rne(wp[0] * gamma, wp[1] * gamma,
                                   wp[2] * gamma, wp[3] * gamma);
    }

  const unsigned short* phib = phi_pad + ((size_t)b * MPTS << 4);
  const unsigned short* gb   = g_f + (size_t)b * (MPTS / 16) * 512;

  float4v acc00 = {0.f, 0.f, 0.f, 0.f}, acc01 = acc00, acc10 = acc00, acc11 = acc00;
  float lsum0 = 0.f, lsum1 = 0.f;

  gl_lds16(gb + 0 * 2048 + wid * 512 + lane * 8, &s_g[0][wid * 512]);
  if (wid < 2)
    gl_lds16(phib + 0 * 1024 + wid * 512 + lane * 8, &s_phi[0][wid * 512]);
  __syncthreads();

#pragma unroll 1
  for (int t = 0; t < NTILE; ++t) {
    int cur = t & 1;
    if (t + 1 < NTILE) {
      gl_lds16(gb + (size_t)(t + 1) * 2048 + wid * 512 + lane * 8,
               &s_g[cur ^ 1][wid * 512]);
      if (wid < 2)
        gl_lds16(phib + (size_t)(t + 1) * 1024 + wid * 512 + lane * 8,
                 &s_phi[cur ^ 1][wid * 512]);
    }
#pragma unroll
    for (int st = 0; st < 4; ++st) {
      int fb = st * 256 + col * 16 + l4 * 4;
      short4v pf = *(const short4v*)&s_phi[cur][fb];
      int gv = st * 512 + col * 16 + l4 * 4;
      short4v g0 = *(const short4v*)&s_g[cur][gv];
      short4v g1 = *(const short4v*)&s_g[cur][gv + 256];

      float4v zero4 = {0.f, 0.f, 0.f, 0.f};
      float4v s0 = __builtin_amdgcn_mfma_f32_16x16x16bf16_1k(pf, bt0, zero4, 0, 0, 0);
      float4v s1 = __builtin_amdgcn_mfma_f32_16x16x16bf16_1k(pf, bt1, zero4, 0, 0, 0);

      float p00 = __builtin_amdgcn_exp2f(s0[0]);
      float p01 = __builtin_amdgcn_exp2f(s0[1]);
      float p02 = __builtin_amdgcn_exp2f(s0[2]);
      float p03 = __builtin_amdgcn_exp2f(s0[3]);
      float p10 = __builtin_amdgcn_exp2f(s1[0]);
      float p11 = __builtin_amdgcn_exp2f(s1[1]);
      float p12 = __builtin_amdgcn_exp2f(s1[2]);
      float p13 = __builtin_amdgcn_exp2f(s1[3]);
      lsum0 += (p00 + p01) + (p02 + p03);
      lsum1 += (p10 + p11) + (p12 + p13);
      short4v pb0 = pack_bf16_trunc(p00, p01, p02, p03);
      short4v pb1 = pack_bf16_trunc(p10, p11, p12, p13);

      acc00 = __builtin_amdgcn_mfma_f32_16x16x16bf16_1k(g0, pb0, acc00, 0, 0, 0);
      acc01 = __builtin_amdgcn_mfma_f32_16x16x16bf16_1k(g0, pb1, acc01, 0, 0, 0);
      acc10 = __builtin_amdgcn_mfma_f32_16x16x16bf16_1k(g1, pb0, acc10, 0, 0, 0);
      acc11 = __builtin_amdgcn_mfma_f32_16x16x16bf16_1k(g1, pb1, acc11, 0, 0, 0);
    }
    __syncthreads();
  }

  lsum0 += __shfl_xor(lsum0, 16, 64);
  lsum0 += __shfl_xor(lsum0, 32, 64);
  lsum1 += __shfl_xor(lsum1, 16, 64);
  lsum1 += __shfl_xor(lsum1, 32, 64);
  float li0 = 1.0f / lsum0;
  float li1 = 1.0f / lsum1;

  short4v onb00 = pack_bf16_rne(acc00[0] * li0, acc00[1] * li0, acc00[2] * li0, acc00[3] * li0);
  short4v onb01 = pack_bf16_rne(acc01[0] * li1, acc01[1] * li1, acc01[2] * li1, acc01[3] * li1);
  short4v onb10 = pack_bf16_rne(acc10[0] * li0, acc10[1] * li0, acc10[2] * li0, acc10[3] * li0);
  short4v onb11 = pack_bf16_rne(acc11[0] * li1, acc11[1] * li1, acc11[2] * li1, acc11[3] * li1);

  float4v zero4 = {0.f, 0.f, 0.f, 0.f};
#pragma unroll
  for (int cot = 0; cot < 4; ++cot) {
#pragma unroll
    for (int nt = 0; nt < 2; ++nt) {
      short4v bfrag0 = nt ? onb01 : onb00;
      short4v bfrag1 = nt ? onb11 : onb10;
      float4v d = __builtin_amdgcn_mfma_f32_16x16x16bf16_1k(wo[cot][0], bfrag0, zero4, 0, 0, 0);
      d = __builtin_amdgcn_mfma_f32_16x16x16bf16_1k(wo[cot][1], bfrag1, d, 0, 0, 0);
      int n = qb + nt * 16 + col;
      size_t base = (size_t)(b * C_IN + cot * 16 + l4 * 4) * NPTS + n;
      const float* xp = x + base;
      float* op = out + base;
#pragma unroll
      for (int e = 0; e < 4; ++e) {
        op[(size_t)e * NPTS] = d[e] + xp[(size_t)e * NPTS];
      }
    }
  }
}

extern "C" void kernel_launch(void* const* d_in, const int* in_sizes, int n_in,
                              void* d_out, int out_size, void* d_ws, size_t ws_size,
                              hipStream_t stream) {
  const float* x       = (const float*)d_in[0];
  const float* w_theta = (const float*)d_in[1];
  const float* w_phi   = (const float*)d_in[2];
  const float* w_g     = (const float*)d_in[3];
  const float* w_o     = (const float*)d_in[4];
  const float* gamma   = (const float*)d_in[5];
  float* out = (float*)d_out;

  char* ws = (char*)d_ws;
  unsigned short* theta_pad = (unsigned short*)ws;            ws += (size_t)NB * NPTS * 16 * 2;  // 2 MB
  unsigned short* phi_pad   = (unsigned short*)ws;            ws += (size_t)NB * MPTS * 16 * 2;  // 256 KB
  unsigned short* g_f       = (unsigned short*)ws;            ws += (size_t)NB * MPTS * 32 * 2;  // 512 KB
  size_t base_need = (size_t)(ws - (char*)d_ws);
  float4v* opart = (float4v*)ws;                              ws += (size_t)NB * KSPLIT * QTILES * 4 * 64 * 16; // 16 MB
  float*   lbuf  = (float*)ws;                                ws += (size_t)NB * KSPLIT * QTILES * 32 * 4;      // 1 MB
  size_t split_need = (size_t)(ws - (char*)d_ws);

  prep_fused<<<dim3(576), dim3(256), 0, stream>>>(
      x, w_theta, w_phi, w_g, theta_pad, phi_pad, g_f);

  if (ws_size >= split_need) {
    attn_split<<<dim3(NPTS / 128, NB * KSPLIT), dim3(256), 0, stream>>>(
        theta_pad, phi_pad, g_f, opart, lbuf);
    attn_combine<<<dim3(NPTS / 128, NB), dim3(256), 0, stream>>>(
        x, w_o, gamma, opart, lbuf, out);
  } else if (ws_size >= base_need) {
    attn_mfma<<<dim3(NPTS / 128, NB), dim3(256), 0, stream>>>(
        x, w_o, gamma, theta_pad, phi_pad, g_f, out);
  }
}